// Round 9
// baseline (381.525 us; speedup 1.0000x reference)
//
#include <hip/hip_runtime.h>

typedef unsigned short u16;
typedef __attribute__((ext_vector_type(8))) short short8;
typedef __attribute__((ext_vector_type(8))) unsigned short ushort8v;
typedef __attribute__((ext_vector_type(4))) float f32x4;

#define B_ 8
#define T_ 256
#define U_ 64
#define E_ 512
#define J_ 640
#define V_ 1024
#define NT 20

__device__ __forceinline__ u16 f2bf(float f) {
  unsigned int u = __float_as_uint(f);
  u += 0x7fffu + ((u >> 16) & 1u);   // round-to-nearest-even
  return (u16)(u >> 16);
}

__device__ __forceinline__ void gload16(const void* g, void* l) {
  __builtin_amdgcn_global_load_lds((const __attribute__((address_space(1))) void*)g,
                                   (__attribute__((address_space(3))) void*)l,
                                   16, 0, 0);
}

// ---------------- fused cast fp32 -> bf16 for all 5 inputs (dsts contiguous in ws) --------
__global__ __launch_bounds__(256) void cast5_k(const float4* __restrict__ s0,
                                               const float4* __restrict__ s1,
                                               const float4* __restrict__ s2,
                                               const float4* __restrict__ s3,
                                               const float4* __restrict__ s4,
                                               ushort4* __restrict__ dst) {
  int i = blockIdx.x * 256 + threadIdx.x;
  const int st = gridDim.x * 256;
  for (; i < 655360; i += st) {
    const float4* s; int off;
    if (i < 262144)      { s = s0; off = 0; }
    else if (i < 327680) { s = s1; off = 262144; }
    else if (i < 409600) { s = s2; off = 327680; }
    else if (i < 491520) { s = s3; off = 409600; }
    else                 { s = s4; off = 491520; }
    float4 v = s[i - off];
    ushort4 o;
    o.x = f2bf(v.x); o.y = f2bf(v.y); o.z = f2bf(v.z); o.w = f2bf(v.w);
    dst[i] = o;
  }
}

// ---------------- projection GEMM (small, latency-tolerant) ----------------
__global__ __launch_bounds__(256) void proj_k(const u16* __restrict__ X,
                                              const u16* __restrict__ W,
                                              float* __restrict__ C) {
  __shared__ __align__(16) u16 As[128 * 32];
  __shared__ __align__(16) u16 Bs[128 * 32];
  const int tid = threadIdx.x;
  const int w = tid >> 6, lane = tid & 63;
  const int wr = w >> 1, wc = w & 1;
  const int m0 = blockIdx.x * 128, n0 = blockIdx.y * 128;
  const int lr = lane & 15, lk = lane >> 4;
  const int r4 = tid >> 2, kq = tid & 3;

  f32x4 acc[4][4] = {};

  for (int ks = 0; ks < E_ / 32; ++ks) {
    const int k0 = ks * 32;
    gload16(X + (size_t)(m0 + r4) * E_ + k0 + kq * 8, (char*)As + w * 1024);
    gload16(X + (size_t)(m0 + 64 + r4) * E_ + k0 + kq * 8, (char*)As + 4096 + w * 1024);
    gload16(W + (size_t)(n0 + r4) * E_ + k0 + kq * 8, (char*)Bs + w * 1024);
    gload16(W + (size_t)(n0 + 64 + r4) * E_ + k0 + kq * 8, (char*)Bs + 4096 + w * 1024);
    __syncthreads();
    short8 a[4], bb[4];
#pragma unroll
    for (int m = 0; m < 4; ++m)
      a[m] = *(const short8*)&As[(wr * 64 + m * 16 + lr) * 32 + lk * 8];
#pragma unroll
    for (int n = 0; n < 4; ++n)
      bb[n] = *(const short8*)&Bs[(wc * 64 + n * 16 + lr) * 32 + lk * 8];
#pragma unroll
    for (int m = 0; m < 4; ++m)
#pragma unroll
      for (int n = 0; n < 4; ++n)
        acc[m][n] = __builtin_amdgcn_mfma_f32_16x16x32_bf16(a[m], bb[n], acc[m][n], 0, 0, 0);
    __syncthreads();
  }

#pragma unroll
  for (int m = 0; m < 4; ++m) {
    const int row = m0 + wr * 64 + m * 16 + lk * 4;
#pragma unroll
    for (int n = 0; n < 4; ++n) {
      const int col = n0 + wc * 64 + n * 16 + lr;
#pragma unroll
      for (int i = 0; i < 4; ++i)
        C[(size_t)(row + i) * J_ + col] = acc[m][n][i];
    }
  }
}

// ---------------- fused joint: silu A-panel in LDS once, then barrier-free GEMM ----------
// Block = one (b,t): rows m0=bt*64 .. +63 (u-dim). A[u][j] = silu(ep[bt][j]+pp[b*64+u][j])
// lives in LDS (80 KiB, chunk-XOR swizzled). B-frags straight from L2-resident Wo (bf16).
// 8 waves, each owns 64x128 output (2 chunks of 64 cols). K pipelined, distance-2 B
// prefetch (B0..B3), ping-pong A-frags. ZERO barriers in the main loop.
__global__ __launch_bounds__(512, 2) void fused_k(const float* __restrict__ ep,
                                                  const float* __restrict__ pp,
                                                  const u16* __restrict__ Wo,
                                                  float* __restrict__ out) {
  __shared__ __align__(16) u16 Alds[64 * 640];   // 80 KiB
  const int tid = threadIdx.x;
  const int w = tid >> 6, lane = tid & 63;
  const int lr = lane & 15, lk = lane >> 4;
  const int bt = blockIdx.x;                 // b*256 + t
  const int b = bt >> 8;
  const size_t m0 = (size_t)bt * 64;

  // ---- phase 1: build swizzled A-panel (one pass, 10 units/thread) ----
  const float* eprow = ep + (size_t)bt * J_;
  const float* pbase = pp + (size_t)b * 64 * J_;
#pragma unroll
  for (int it = 0; it < 10; ++it) {
    const int unit = tid + it * 512;         // 5120 units = 64 rows x 80 chunks
    const int row = unit / 80;
    const int c = unit - row * 80;
    union { float4 v[2]; float f[8]; } Ee, Pp;
    Ee.v[0] = *(const float4*)(eprow + c * 8);
    Ee.v[1] = *(const float4*)(eprow + c * 8 + 4);
    Pp.v[0] = *(const float4*)(pbase + (size_t)row * J_ + c * 8);
    Pp.v[1] = *(const float4*)(pbase + (size_t)row * J_ + c * 8 + 4);
    union { ushort8v v; u16 s[8]; } R;
#pragma unroll
    for (int j = 0; j < 8; ++j) {
      float x = Ee.f[j] + Pp.f[j];
      R.s[j] = f2bf(x * __builtin_amdgcn_rcpf(1.0f + __expf(-x)));
    }
    *(ushort8v*)&Alds[row * 640 + ((c ^ (row & 7)) << 3)] = R.v;
  }
  __syncthreads();                            // the ONLY barrier

  // ---- phase 2: barrier-free K-pipelined GEMM ----
  const int rx = lr & 7;
  int arow[4];
#pragma unroll
  for (int mq = 0; mq < 4; ++mq) arow[mq] = (mq * 16 + lr) * 640;

#define AR(aF, ks)                                                             \
  do {                                                                         \
    _Pragma("unroll")                                                          \
    for (int mq = 0; mq < 4; ++mq)                                             \
      aF[mq] = *(const short8*)&Alds[arow[mq] + ((((ks) * 4 + lk) ^ rx) << 3)];\
  } while (0)

#define BL(bF, ks)                                                             \
  do {                                                                         \
    _Pragma("unroll")                                                          \
    for (int nq = 0; nq < 4; ++nq)                                             \
      bF[nq] = *(const short8*)(bp + (size_t)nq * 16 * J_ + (ks) * 32);        \
  } while (0)

#define MM(aF, bF)                                                             \
  do {                                                                         \
    __builtin_amdgcn_s_setprio(1);                                             \
    _Pragma("unroll")                                                          \
    for (int mq = 0; mq < 4; ++mq)                                             \
      _Pragma("unroll")                                                        \
      for (int nq = 0; nq < 4; ++nq)                                           \
        acc[mq][nq] = __builtin_amdgcn_mfma_f32_16x16x32_bf16(aF[mq], bF[nq],  \
                                                              acc[mq][nq], 0, 0, 0); \
    __builtin_amdgcn_s_setprio(0);                                             \
  } while (0)

#pragma unroll 1
  for (int c2 = 0; c2 < 2; ++c2) {
    const int col0 = w * 128 + c2 * 64;
    const u16* bp = Wo + (size_t)(col0 + lr) * J_ + lk * 8;

    f32x4 acc[4][4] = {};
    short8 B0[4], B1[4], B2[4], B3[4], aE[4], aO[4];
    BL(B0, 0); BL(B1, 1);
    AR(aE, 0);
#pragma unroll 1
    for (int ks = 0; ks < NT; ks += 4) {
      BL(B2, ks + 2); AR(aO, ks + 1); MM(aE, B0);
      BL(B3, ks + 3); AR(aE, ks + 2); MM(aO, B1);
      if (ks + 4 < NT) BL(B0, ks + 4);
      AR(aO, ks + 3); MM(aE, B2);
      if (ks + 4 < NT) { BL(B1, ks + 5); AR(aE, ks + 4); }
      MM(aO, B3);
    }

#pragma unroll
    for (int mq = 0; mq < 4; ++mq) {
      const size_t row = m0 + mq * 16 + lk * 4;
#pragma unroll
      for (int nq = 0; nq < 4; ++nq) {
        const int col = col0 + nq * 16 + lr;
#pragma unroll
        for (int i = 0; i < 4; ++i)
          out[(row + i) * V_ + col] = acc[mq][nq][i];
      }
    }
  }
#undef AR
#undef BL
#undef MM
}

extern "C" void kernel_launch(void* const* d_in, const int* in_sizes, int n_in,
                              void* d_out, int out_size, void* d_ws, size_t ws_size,
                              hipStream_t stream) {
  const float* enc = (const float*)d_in[0];   // [8,256,512]
  const float* pred = (const float*)d_in[1];  // [8,64,512]
  const float* We = (const float*)d_in[2];    // [640,512]
  const float* Wp = (const float*)d_in[3];    // [640,512]
  const float* Wo = (const float*)d_in[4];    // [1024,640]
  float* out = (float*)d_out;                 // [8,256,64,1024]

  char* ws = (char*)d_ws;
  u16* enc_bf = (u16*)ws;                     // 2,097,152 B
  u16* pred_bf = (u16*)(ws + 2097152);        //   524,288 B
  u16* We_bf = (u16*)(ws + 2621440);          //   655,360 B
  u16* Wp_bf = (u16*)(ws + 3276800);          //   655,360 B
  u16* Wo_bf = (u16*)(ws + 3932160);          // 1,310,720 B -> ends 5,242,880
  float* ep = (float*)(ws + 5242880);         // 5,242,880 B  [2048][640]
  float* pp = (float*)(ws + 10485760);        // 1,310,720 B  [512][640] -> ends 11,796,480

  cast5_k<<<2048, 256, 0, stream>>>((const float4*)enc, (const float4*)pred,
                                    (const float4*)We, (const float4*)Wp,
                                    (const float4*)Wo, (ushort4*)ws);

  proj_k<<<dim3(16, 5), 256, 0, stream>>>(enc_bf, We_bf, ep);  // [2048][640]
  proj_k<<<dim3(4, 5), 256, 0, stream>>>(pred_bf, Wp_bf, pp);  // [512][640]

  fused_k<<<2048, 512, 0, stream>>>(ep, pp, Wo_bf, out);
}

// Round 10
// 376.969 us; speedup vs baseline: 1.0121x; 1.0121x over previous
//
#include <hip/hip_runtime.h>

typedef unsigned short u16;
typedef __attribute__((ext_vector_type(8))) short short8;
typedef __attribute__((ext_vector_type(8))) unsigned short ushort8v;
typedef __attribute__((ext_vector_type(4))) float f32x4;

#define B_ 8
#define T_ 256
#define U_ 64
#define E_ 512
#define J_ 640
#define V_ 1024
#define NKT 10   // 640/64 K-tiles

__device__ __forceinline__ u16 f2bf(float f) {
  unsigned int u = __float_as_uint(f);
  u += 0x7fffu + ((u >> 16) & 1u);   // round-to-nearest-even
  return (u16)(u >> 16);
}

__device__ __forceinline__ void gload16(const void* g, void* l) {
  __builtin_amdgcn_global_load_lds((const __attribute__((address_space(1))) void*)g,
                                   (__attribute__((address_space(3))) void*)l,
                                   16, 0, 0);
}

// ---------------- fused cast fp32 -> bf16 for all 5 inputs ----------------
__global__ __launch_bounds__(256) void cast5_k(const float4* __restrict__ s0,
                                               const float4* __restrict__ s1,
                                               const float4* __restrict__ s2,
                                               const float4* __restrict__ s3,
                                               const float4* __restrict__ s4,
                                               ushort4* __restrict__ dst) {
  int i = blockIdx.x * 256 + threadIdx.x;
  const int st = gridDim.x * 256;
  for (; i < 655360; i += st) {
    const float4* s; int off;
    if (i < 262144)      { s = s0; off = 0; }
    else if (i < 327680) { s = s1; off = 262144; }
    else if (i < 409600) { s = s2; off = 327680; }
    else if (i < 491520) { s = s3; off = 409600; }
    else                 { s = s4; off = 491520; }
    float4 v = s[i - off];
    ushort4 o;
    o.x = f2bf(v.x); o.y = f2bf(v.y); o.z = f2bf(v.z); o.w = f2bf(v.w);
    dst[i] = o;
  }
}

// ---------------- projection GEMM ----------------
__global__ __launch_bounds__(256) void proj_k(const u16* __restrict__ X,
                                              const u16* __restrict__ W,
                                              float* __restrict__ C) {
  __shared__ __align__(16) u16 As[128 * 32];
  __shared__ __align__(16) u16 Bs[128 * 32];
  const int tid = threadIdx.x;
  const int w = tid >> 6, lane = tid & 63;
  const int wr = w >> 1, wc = w & 1;
  const int m0 = blockIdx.x * 128, n0 = blockIdx.y * 128;
  const int lr = lane & 15, lk = lane >> 4;
  const int r4 = tid >> 2, kq = tid & 3;

  f32x4 acc[4][4] = {};

  for (int ks = 0; ks < E_ / 32; ++ks) {
    const int k0 = ks * 32;
    gload16(X + (size_t)(m0 + r4) * E_ + k0 + kq * 8, (char*)As + w * 1024);
    gload16(X + (size_t)(m0 + 64 + r4) * E_ + k0 + kq * 8, (char*)As + 4096 + w * 1024);
    gload16(W + (size_t)(n0 + r4) * E_ + k0 + kq * 8, (char*)Bs + w * 1024);
    gload16(W + (size_t)(n0 + 64 + r4) * E_ + k0 + kq * 8, (char*)Bs + 4096 + w * 1024);
    __syncthreads();
    short8 a[4], bb[4];
#pragma unroll
    for (int m = 0; m < 4; ++m)
      a[m] = *(const short8*)&As[(wr * 64 + m * 16 + lr) * 32 + lk * 8];
#pragma unroll
    for (int n = 0; n < 4; ++n)
      bb[n] = *(const short8*)&Bs[(wc * 64 + n * 16 + lr) * 32 + lk * 8];
#pragma unroll
    for (int m = 0; m < 4; ++m)
#pragma unroll
      for (int n = 0; n < 4; ++n)
        acc[m][n] = __builtin_amdgcn_mfma_f32_16x16x32_bf16(a[m], bb[n], acc[m][n], 0, 0, 0);
    __syncthreads();
  }

#pragma unroll
  for (int m = 0; m < 4; ++m) {
    const int row = m0 + wr * 64 + m * 16 + lk * 4;
#pragma unroll
    for (int n = 0; n < 4; ++n) {
      const int col = n0 + wc * 64 + n * 16 + lr;
#pragma unroll
      for (int i = 0; i < 4; ++i)
        C[(size_t)(row + i) * J_ + col] = acc[m][n][i];
    }
  }
}

// ---------------- A materializer ----------------
__global__ __launch_bounds__(256) void silu_k(const float* __restrict__ ep,
                                              const float* __restrict__ pp,
                                              u16* __restrict__ A, int nUnits) {
  int i = blockIdx.x * 256 + threadIdx.x;
  const int st = gridDim.x * 256;
  for (; i < nUnits; i += st) {
    const int m = i / 80;
    const int k0 = (i - m * 80) * 8;
    const int b = m >> 14;
    const int t = (m >> 6) & 255;
    const int uu = m & 63;
    const float* e = ep + (size_t)(b * T_ + t) * J_ + k0;
    const float* p = pp + (size_t)(b * U_ + uu) * J_ + k0;
    union { float4 v[2]; float f[8]; } Ee, Pp;
    Ee.v[0] = *(const float4*)e;      Ee.v[1] = *(const float4*)(e + 4);
    Pp.v[0] = *(const float4*)p;      Pp.v[1] = *(const float4*)(p + 4);
    union { ushort8v v; u16 s[8]; } R;
#pragma unroll
    for (int j = 0; j < 8; ++j) {
      float x = Ee.f[j] + Pp.f[j];
      float s = x * __builtin_amdgcn_rcpf(1.0f + __expf(-x));
      R.s[j] = f2bf(s);
    }
    *(ushort8v*)(A + (size_t)m * J_ + k0) = R.v;
  }
}

// ---------------- main GEMM: m201-style 8-phase, 256x256, BK=64, 8 waves ----------------
// 4 half-tile slots [128][64] per operand (128 KiB). Tile t in slots (2t&3,2t+1&3).
// 4 phases per K-tile: {stage 1 half-tile of t+1 | ds_read quadrant | barrier |
// lgkmcnt(0)+sched_barrier | setprio(1) 16 MFMA setprio(0) | barrier}.
// ONE counted vmcnt(2) per K-tile at P0 (in-order queue [t:8][t+1:2]); never 0 in steady state.
// Pow2 row stride (128B) + chunk-XOR c^(row&7) swizzle both sides -> 0 bank conflicts.
__global__ __launch_bounds__(512, 2) void gemm8p_k(const u16* __restrict__ A,
                                                   const u16* __restrict__ Bw,
                                                   float* __restrict__ out) {
  __shared__ __align__(16) u16 As[4][128][64];   // 64 KiB
  __shared__ __align__(16) u16 Bs[4][128][64];   // 64 KiB
  const int tid = threadIdx.x;
  const int w = tid >> 6, lane = tid & 63;
  const int wr = w >> 2, wc = w & 3;            // 2M x 4N waves, wave tile 128x64
  const int lr = lane & 15, lk = lane >> 4;
  const int rx = lr & 7;                        // read swizzle term (= frag row & 7)

  // XCD-bijective swizzle: nwg=2048 = 8 XCDs x 256-chunk; nb inner (A-panel L2 reuse)
  const int bid = blockIdx.x;
  const int wid = (bid & 7) * 256 + (bid >> 3);
  const int mbb = wid >> 2, nbb = wid & 3;
  const size_t m0 = (size_t)mbb * 256;
  const int n0 = nbb * 256;

  // staging: thread covers row rw of each 128-row slot (2 loads/slot: rows 0-63, 64-127);
  // source chunk pre-swizzled so linear dest realizes LDS[r][c] = global chunk c^(r&7)
  const int rw = tid >> 3;
  const int csrc = (tid & 7) ^ (rw & 7);
  const u16* aBase = A + (m0 + rw) * (size_t)J_ + csrc * 8;
  const u16* bBase = Bw + (size_t)(n0 + rw) * J_ + csrc * 8;

  f32x4 acc[8][4] = {};

#define SA(t1, hf)                                                             \
  do {                                                                         \
    const int s_ = (2 * (t1) + (hf)) & 3;                                      \
    const int k0_ = (t1) * 64;                                                 \
    gload16(aBase + (size_t)((hf) * 128) * J_ + k0_,                           \
            (char*)&As[s_][0][0] + tid * 16);                                  \
    gload16(aBase + (size_t)((hf) * 128 + 64) * J_ + k0_,                      \
            (char*)&As[s_][0][0] + 8192 + tid * 16);                           \
  } while (0)
#define SB(t1, hf)                                                             \
  do {                                                                         \
    const int s_ = (2 * (t1) + (hf)) & 3;                                      \
    const int k0_ = (t1) * 64;                                                 \
    gload16(bBase + (size_t)((hf) * 128) * J_ + k0_,                           \
            (char*)&Bs[s_][0][0] + tid * 16);                                  \
    gload16(bBase + (size_t)((hf) * 128 + 64) * J_ + k0_,                      \
            (char*)&Bs[s_][0][0] + 8192 + tid * 16);                           \
  } while (0)

#define AREAD(p)                                                               \
  do {                                                                         \
    aP0[0] = *(const short8*)&As[sa][(2 * (p)) * 16 + lr][((0 + lk) ^ rx) * 8];\
    aP0[1] = *(const short8*)&As[sa][(2 * (p)) * 16 + lr][((4 + lk) ^ rx) * 8];\
    aP1[0] = *(const short8*)&As[sa][(2 * (p) + 1) * 16 + lr][((0 + lk) ^ rx) * 8]; \
    aP1[1] = *(const short8*)&As[sa][(2 * (p) + 1) * 16 + lr][((4 + lk) ^ rx) * 8]; \
  } while (0)

#define PH_MFMA(p)                                                             \
  do {                                                                         \
    __builtin_amdgcn_s_setprio(1);                                             \
    _Pragma("unroll")                                                          \
    for (int nq = 0; nq < 4; ++nq) {                                           \
      acc[2 * (p)][nq] = __builtin_amdgcn_mfma_f32_16x16x32_bf16(aP0[0], bF[nq][0], acc[2 * (p)][nq], 0, 0, 0); \
      acc[2 * (p)][nq] = __builtin_amdgcn_mfma_f32_16x16x32_bf16(aP0[1], bF[nq][1], acc[2 * (p)][nq], 0, 0, 0); \
      acc[2 * (p) + 1][nq] = __builtin_amdgcn_mfma_f32_16x16x32_bf16(aP1[0], bF[nq][0], acc[2 * (p) + 1][nq], 0, 0, 0); \
      acc[2 * (p) + 1][nq] = __builtin_amdgcn_mfma_f32_16x16x32_bf16(aP1[1], bF[nq][1], acc[2 * (p) + 1][nq], 0, 0, 0); \
    }                                                                          \
    __builtin_amdgcn_s_setprio(0);                                             \
  } while (0)

  // prologue: tile 0's 8 loads in flight
  SA(0, 0); SA(0, 1); SB(0, 0); SB(0, 1);

  short8 bF[4][2], aP0[2], aP1[2];

#pragma unroll 1
  for (int t = 0; t < NKT; ++t) {
    const int sa = (2 * t + wr) & 3;
    const int sb = (2 * t + (wc >> 1)) & 3;
    const int brow = (wc & 1) * 64;
    const bool pf = (t + 1 < NKT);

    // ---------------- P0: stage A-half0(t+1) | vmcnt(2) | barrier | read B(8)+A-q0(4) | MFMA
    if (pf) {
      SA(t + 1, 0);
      asm volatile("s_waitcnt vmcnt(2)" ::: "memory");
    } else {
      asm volatile("s_waitcnt vmcnt(0)" ::: "memory");
    }
    __builtin_amdgcn_s_barrier();
    __builtin_amdgcn_sched_barrier(0);
#pragma unroll
    for (int nq = 0; nq < 4; ++nq) {
      bF[nq][0] = *(const short8*)&Bs[sb][brow + nq * 16 + lr][((0 + lk) ^ rx) * 8];
      bF[nq][1] = *(const short8*)&Bs[sb][brow + nq * 16 + lr][((4 + lk) ^ rx) * 8];
    }
    AREAD(0);
    asm volatile("s_waitcnt lgkmcnt(0)" ::: "memory");
    __builtin_amdgcn_sched_barrier(0);
    PH_MFMA(0);
    __builtin_amdgcn_s_barrier();
    __builtin_amdgcn_sched_barrier(0);

    // ---------------- P1: read A-q1 | stage A-half1(t+1) | barrier | MFMA
    AREAD(1);
    if (pf) SA(t + 1, 1);
    __builtin_amdgcn_s_barrier();
    asm volatile("s_waitcnt lgkmcnt(0)" ::: "memory");
    __builtin_amdgcn_sched_barrier(0);
    PH_MFMA(1);
    __builtin_amdgcn_s_barrier();
    __builtin_amdgcn_sched_barrier(0);

    // ---------------- P2: read A-q2 | stage B-half0(t+1) | barrier | MFMA
    AREAD(2);
    if (pf) SB(t + 1, 0);
    __builtin_amdgcn_s_barrier();
    asm volatile("s_waitcnt lgkmcnt(0)" ::: "memory");
    __builtin_amdgcn_sched_barrier(0);
    PH_MFMA(2);
    __builtin_amdgcn_s_barrier();
    __builtin_amdgcn_sched_barrier(0);

    // ---------------- P3: read A-q3 | stage B-half1(t+1) | barrier | MFMA
    AREAD(3);
    if (pf) SB(t + 1, 1);
    __builtin_amdgcn_s_barrier();
    asm volatile("s_waitcnt lgkmcnt(0)" ::: "memory");
    __builtin_amdgcn_sched_barrier(0);
    PH_MFMA(3);
    __builtin_amdgcn_s_barrier();
    __builtin_amdgcn_sched_barrier(0);
  }
#undef SA
#undef SB
#undef AREAD
#undef PH_MFMA

#pragma unroll
  for (int m = 0; m < 8; ++m) {
    const size_t row = m0 + wr * 128 + m * 16 + lk * 4;
#pragma unroll
    for (int n = 0; n < 4; ++n) {
      const int col = n0 + wc * 64 + n * 16 + lr;
#pragma unroll
      for (int i = 0; i < 4; ++i)
        out[(row + i) * V_ + col] = acc[m][n][i];
    }
  }
}

// ---------------- fallback fused kernel (round-1) if ws too small ----------------
__global__ __launch_bounds__(256) void joint_k(const float* __restrict__ ep,
                                               const float* __restrict__ pp,
                                               const u16* __restrict__ Wo,
                                               float* __restrict__ out) {
  __shared__ __align__(16) u16 As[128 * 40];
  __shared__ __align__(16) u16 Bs[128 * 32];
  const int tid = threadIdx.x;
  const int w = tid >> 6, lane = tid & 63;
  const int wr = w >> 1, wc = w & 1;
  const int bid = blockIdx.x;
  const int nb = bid & 7;
  const int mb = bid >> 3;
  const int b = mb >> 7;
  const int t0 = (mb & 127) * 2;
  const int n0 = nb * 128;
  const int lr = lane & 15, lk = lane >> 4;
  const int r = tid >> 1, h = tid & 1;
  const float* eprow = ep + (size_t)((b * T_ + t0 + (r >> 6)) * J_ + h * 16);
  const float* pprow = pp + (size_t)((b * U_ + (r & 63)) * J_ + h * 16);
  u16* awp = &As[r * 40 + h * 16];
  const int r4 = tid >> 2, kq = tid & 3;

  f32x4 acc[4][4] = {};

  for (int ks = 0; ks < J_ / 32; ++ks) {
    const int k0 = ks * 32;
    gload16(Wo + (size_t)(n0 + r4) * J_ + k0 + kq * 8, (char*)Bs + w * 1024);
    gload16(Wo + (size_t)(n0 + 64 + r4) * J_ + k0 + kq * 8, (char*)Bs + 4096 + w * 1024);
    union { float4 v[4]; float f[16]; } Ee, Pp;
#pragma unroll
    for (int j = 0; j < 4; ++j) {
      Ee.v[j] = *(const float4*)(eprow + k0 + j * 4);
      Pp.v[j] = *(const float4*)(pprow + k0 + j * 4);
    }
    union { ushort8v v[2]; u16 s[16]; } R;
#pragma unroll
    for (int j = 0; j < 16; ++j) {
      float x = Ee.f[j] + Pp.f[j];
      float s = x * __builtin_amdgcn_rcpf(1.0f + __expf(-x));
      R.s[j] = f2bf(s);
    }
    *(ushort8v*)awp = R.v[0];
    *(ushort8v*)(awp + 8) = R.v[1];
    __syncthreads();

    short8 a[4], bb[4];
#pragma unroll
    for (int m = 0; m < 4; ++m)
      a[m] = *(const short8*)&As[(wr * 64 + m * 16 + lr) * 40 + lk * 8];
#pragma unroll
    for (int n = 0; n < 4; ++n)
      bb[n] = *(const short8*)&Bs[(wc * 64 + n * 16 + lr) * 32 + lk * 8];
#pragma unroll
    for (int m = 0; m < 4; ++m)
#pragma unroll
      for (int n = 0; n < 4; ++n)
        acc[m][n] = __builtin_amdgcn_mfma_f32_16x16x32_bf16(a[m], bb[n], acc[m][n], 0, 0, 0);
    __syncthreads();
  }

  const size_t mbase = (size_t)mb * 128;
#pragma unroll
  for (int m = 0; m < 4; ++m) {
    const size_t row = mbase + wr * 64 + m * 16 + lk * 4;
#pragma unroll
    for (int n = 0; n < 4; ++n) {
      const int col = n0 + wc * 64 + n * 16 + lr;
#pragma unroll
      for (int i = 0; i < 4; ++i)
        out[(row + i) * V_ + col] = acc[m][n][i];
    }
  }
}

extern "C" void kernel_launch(void* const* d_in, const int* in_sizes, int n_in,
                              void* d_out, int out_size, void* d_ws, size_t ws_size,
                              hipStream_t stream) {
  const float* enc = (const float*)d_in[0];   // [8,256,512]
  const float* pred = (const float*)d_in[1];  // [8,64,512]
  const float* We = (const float*)d_in[2];    // [640,512]
  const float* Wp = (const float*)d_in[3];    // [640,512]
  const float* Wo = (const float*)d_in[4];    // [1024,640]
  float* out = (float*)d_out;                 // [8,256,64,1024]

  char* ws = (char*)d_ws;
  u16* enc_bf = (u16*)ws;                     // 2,097,152 B
  u16* pred_bf = (u16*)(ws + 2097152);        //   524,288 B
  u16* We_bf = (u16*)(ws + 2621440);          //   655,360 B
  u16* Wp_bf = (u16*)(ws + 3276800);          //   655,360 B
  u16* Wo_bf = (u16*)(ws + 3932160);          // 1,310,720 B -> ends 5,242,880
  float* ep = (float*)(ws + 5242880);         // 5,242,880 B  [2048][640]
  float* pp = (float*)(ws + 10485760);        // 1,310,720 B  [512][640] -> ends 11,796,480
  u16* A_bf = (u16*)(ws + 12582912);          // 167,772,160 B [131072][640]

  cast5_k<<<2048, 256, 0, stream>>>((const float4*)enc, (const float4*)pred,
                                    (const float4*)We, (const float4*)Wp,
                                    (const float4*)Wo, (ushort4*)ws);

  proj_k<<<dim3(16, 5), 256, 0, stream>>>(enc_bf, We_bf, ep);  // [2048][640]
  proj_k<<<dim3(4, 5), 256, 0, stream>>>(pred_bf, Wp_bf, pp);  // [512][640]

  if (ws_size >= 180355072ull) {
    silu_k<<<2048, 256, 0, stream>>>(ep, pp, A_bf, 10485760);
    gemm8p_k<<<2048, 512, 0, stream>>>(A_bf, Wo_bf, out);
  } else {
    joint_k<<<8192, 256, 0, stream>>>(ep, pp, Wo_bf, out);
  }
}

// Round 11
// 238.216 us; speedup vs baseline: 1.6016x; 1.5825x over previous
//
#include <hip/hip_runtime.h>

typedef unsigned short u16;
typedef __attribute__((ext_vector_type(8))) short short8;
typedef __attribute__((ext_vector_type(8))) unsigned short ushort8v;
typedef __attribute__((ext_vector_type(4))) float f32x4;

#define B_ 8
#define T_ 256
#define U_ 64
#define E_ 512
#define J_ 640
#define V_ 1024
#define NT 20

__device__ __forceinline__ u16 f2bf(float f) {
  unsigned int u = __float_as_uint(f);
  u += 0x7fffu + ((u >> 16) & 1u);   // round-to-nearest-even
  return (u16)(u >> 16);
}

__device__ __forceinline__ void gload16(const void* g, void* l) {
  __builtin_amdgcn_global_load_lds((const __attribute__((address_space(1))) void*)g,
                                   (__attribute__((address_space(3))) void*)l,
                                   16, 0, 0);
}

// ---------------- fused cast fp32 -> bf16 for all 5 inputs (dsts contiguous in ws) --------
__global__ __launch_bounds__(256) void cast5_k(const float4* __restrict__ s0,
                                               const float4* __restrict__ s1,
                                               const float4* __restrict__ s2,
                                               const float4* __restrict__ s3,
                                               const float4* __restrict__ s4,
                                               ushort4* __restrict__ dst) {
  int i = blockIdx.x * 256 + threadIdx.x;
  const int st = gridDim.x * 256;
  for (; i < 655360; i += st) {
    const float4* s; int off;
    if (i < 262144)      { s = s0; off = 0; }
    else if (i < 327680) { s = s1; off = 262144; }
    else if (i < 409600) { s = s2; off = 327680; }
    else if (i < 491520) { s = s3; off = 409600; }
    else                 { s = s4; off = 491520; }
    float4 v = s[i - off];
    ushort4 o;
    o.x = f2bf(v.x); o.y = f2bf(v.y); o.z = f2bf(v.z); o.w = f2bf(v.w);
    dst[i] = o;
  }
}

// ---------------- projection GEMM (small, latency-tolerant) ----------------
__global__ __launch_bounds__(256) void proj_k(const u16* __restrict__ X,
                                              const u16* __restrict__ W,
                                              float* __restrict__ C) {
  __shared__ __align__(16) u16 As[128 * 32];
  __shared__ __align__(16) u16 Bs[128 * 32];
  const int tid = threadIdx.x;
  const int w = tid >> 6, lane = tid & 63;
  const int wr = w >> 1, wc = w & 1;
  const int m0 = blockIdx.x * 128, n0 = blockIdx.y * 128;
  const int lr = lane & 15, lk = lane >> 4;
  const int r4 = tid >> 2, kq = tid & 3;

  f32x4 acc[4][4] = {};

  for (int ks = 0; ks < E_ / 32; ++ks) {
    const int k0 = ks * 32;
    gload16(X + (size_t)(m0 + r4) * E_ + k0 + kq * 8, (char*)As + w * 1024);
    gload16(X + (size_t)(m0 + 64 + r4) * E_ + k0 + kq * 8, (char*)As + 4096 + w * 1024);
    gload16(W + (size_t)(n0 + r4) * E_ + k0 + kq * 8, (char*)Bs + w * 1024);
    gload16(W + (size_t)(n0 + 64 + r4) * E_ + k0 + kq * 8, (char*)Bs + 4096 + w * 1024);
    __syncthreads();
    short8 a[4], bb[4];
#pragma unroll
    for (int m = 0; m < 4; ++m)
      a[m] = *(const short8*)&As[(wr * 64 + m * 16 + lr) * 32 + lk * 8];
#pragma unroll
    for (int n = 0; n < 4; ++n)
      bb[n] = *(const short8*)&Bs[(wc * 64 + n * 16 + lr) * 32 + lk * 8];
#pragma unroll
    for (int m = 0; m < 4; ++m)
#pragma unroll
      for (int n = 0; n < 4; ++n)
        acc[m][n] = __builtin_amdgcn_mfma_f32_16x16x32_bf16(a[m], bb[n], acc[m][n], 0, 0, 0);
    __syncthreads();
  }

#pragma unroll
  for (int m = 0; m < 4; ++m) {
    const int row = m0 + wr * 64 + m * 16 + lk * 4;
#pragma unroll
    for (int n = 0; n < 4; ++n) {
      const int col = n0 + wc * 64 + n * 16 + lr;
#pragma unroll
      for (int i = 0; i < 4; ++i)
        C[(size_t)(row + i) * J_ + col] = acc[m][n][i];
    }
  }
}

// ---------------- Wo fragment pre-pack ----------------
// pk[((vt*20+ks)*4+nq)*512 + lane*8 + e] = Wo[vt*64+nq*16+(lane&15)][ks*32+(lane>>4)*8+e]
// -> a wave's B-frag (vt,ks,nq) is ONE contiguous 1KB block: lane reads 16B at lane*16.
__global__ __launch_bounds__(256) void pack_k(const u16* __restrict__ Wo,
                                              u16* __restrict__ pk) {
  const int u = blockIdx.x * 256 + threadIdx.x;   // 81920 units of short8
  const int l = u & 63;
  int r = u >> 6;
  const int nq = r & 3;  r >>= 2;
  const int ks = r % 20;
  const int vt = r / 20;
  const int v = vt * 64 + nq * 16 + (l & 15);
  const int k = ks * 32 + (l >> 4) * 8;
  *(short8*)(pk + (size_t)u * 8) = *(const short8*)(Wo + (size_t)v * J_ + k);
}

// ---------------- fused joint: silu A-panel in LDS once, barrier-free GEMM, packed B ------
// Block = one (b,t): 64 rows. A[u][j]=silu(ep[bt][j]+pp[b*64+u][j]) in LDS (80 KiB,
// chunk-XOR swizzled). B-frags: single coalesced 1KB loads from L2-resident pack.
// 8 waves x (64 rows x 128 cols as 2 chunks). Distance-2 B prefetch, ping-pong A-frags.
// ZERO barriers in the main loop -> waves de-phase; LDS/L2/MFMA pipes overlap across waves.
__global__ __launch_bounds__(512, 2) void fused2_k(const float* __restrict__ ep,
                                                   const float* __restrict__ pp,
                                                   const u16* __restrict__ pk,
                                                   float* __restrict__ out) {
  __shared__ __align__(16) u16 Alds[64 * 640];   // 80 KiB
  const int tid = threadIdx.x;
  const int w = tid >> 6, lane = tid & 63;
  const int lr = lane & 15, lk = lane >> 4;
  const int bt = blockIdx.x;                 // b*256 + t
  const int b = bt >> 8;
  const size_t m0 = (size_t)bt * 64;

  // ---- phase 1: build swizzled A-panel (one pass, 10 units/thread) ----
  const float* eprow = ep + (size_t)bt * J_;
  const float* pbase = pp + (size_t)b * 64 * J_;
#pragma unroll
  for (int it = 0; it < 10; ++it) {
    const int unit = tid + it * 512;         // 5120 units = 64 rows x 80 chunks
    const int row = unit / 80;
    const int c = unit - row * 80;
    union { float4 v[2]; float f[8]; } Ee, Pp;
    Ee.v[0] = *(const float4*)(eprow + c * 8);
    Ee.v[1] = *(const float4*)(eprow + c * 8 + 4);
    Pp.v[0] = *(const float4*)(pbase + (size_t)row * J_ + c * 8);
    Pp.v[1] = *(const float4*)(pbase + (size_t)row * J_ + c * 8 + 4);
    union { ushort8v v; u16 s[8]; } R;
#pragma unroll
    for (int j = 0; j < 8; ++j) {
      float x = Ee.f[j] + Pp.f[j];
      R.s[j] = f2bf(x * __builtin_amdgcn_rcpf(1.0f + __expf(-x)));
    }
    *(ushort8v*)&Alds[row * 640 + ((c ^ (row & 7)) << 3)] = R.v;
  }
  __syncthreads();                            // the ONLY barrier

  // ---- phase 2: barrier-free K-pipelined GEMM, coalesced packed-B loads ----
  const int rx = lr & 7;
  int arow[4];
#pragma unroll
  for (int mq = 0; mq < 4; ++mq) arow[mq] = (mq * 16 + lr) * 640;

#define AR(aF, ks)                                                             \
  do {                                                                         \
    _Pragma("unroll")                                                          \
    for (int mq = 0; mq < 4; ++mq)                                             \
      aF[mq] = *(const short8*)&Alds[arow[mq] + ((((ks) * 4 + lk) ^ rx) << 3)];\
  } while (0)

#define BL(bF, ks)                                                             \
  do {                                                                         \
    _Pragma("unroll")                                                          \
    for (int nq = 0; nq < 4; ++nq)                                             \
      bF[nq] = *(const short8*)(bp + (ks) * 2048 + nq * 512);                  \
  } while (0)

#define MM(aF, bF)                                                             \
  do {                                                                         \
    __builtin_amdgcn_s_setprio(1);                                             \
    _Pragma("unroll")                                                          \
    for (int mq = 0; mq < 4; ++mq)                                             \
      _Pragma("unroll")                                                        \
      for (int nq = 0; nq < 4; ++nq)                                           \
        acc[mq][nq] = __builtin_amdgcn_mfma_f32_16x16x32_bf16(aF[mq], bF[nq],  \
                                                              acc[mq][nq], 0, 0, 0); \
    __builtin_amdgcn_s_setprio(0);                                             \
  } while (0)

#pragma unroll 1
  for (int c2 = 0; c2 < 2; ++c2) {
    const int vt = w * 2 + c2;                 // 64-col group 0..15
    const int col0 = vt * 64;
    const u16* bp = pk + (size_t)vt * 40960 + lane * 8;

    f32x4 acc[4][4] = {};
    short8 B0[4], B1[4], B2[4], B3[4], aE[4], aO[4];
    BL(B0, 0); BL(B1, 1);
    AR(aE, 0);
#pragma unroll 1
    for (int ks = 0; ks < NT; ks += 4) {
      BL(B2, ks + 2); AR(aO, ks + 1); MM(aE, B0);
      BL(B3, ks + 3); AR(aE, ks + 2); MM(aO, B1);
      if (ks + 4 < NT) BL(B0, ks + 4);
      AR(aO, ks + 3); MM(aE, B2);
      if (ks + 4 < NT) { BL(B1, ks + 5); AR(aE, ks + 4); }
      MM(aO, B3);
    }

#pragma unroll
    for (int mq = 0; mq < 4; ++mq) {
      const size_t row = m0 + mq * 16 + lk * 4;
#pragma unroll
      for (int nq = 0; nq < 4; ++nq) {
        const int col = col0 + nq * 16 + lr;
#pragma unroll
        for (int i = 0; i < 4; ++i)
          out[(row + i) * V_ + col] = acc[mq][nq][i];
      }
    }
  }
#undef AR
#undef BL
#undef MM
}

extern "C" void kernel_launch(void* const* d_in, const int* in_sizes, int n_in,
                              void* d_out, int out_size, void* d_ws, size_t ws_size,
                              hipStream_t stream) {
  const float* enc = (const float*)d_in[0];   // [8,256,512]
  const float* pred = (const float*)d_in[1];  // [8,64,512]
  const float* We = (const float*)d_in[2];    // [640,512]
  const float* Wp = (const float*)d_in[3];    // [640,512]
  const float* Wo = (const float*)d_in[4];    // [1024,640]
  float* out = (float*)d_out;                 // [8,256,64,1024]

  char* ws = (char*)d_ws;
  u16* enc_bf = (u16*)ws;                     // 2,097,152 B
  u16* pred_bf = (u16*)(ws + 2097152);        //   524,288 B
  u16* We_bf = (u16*)(ws + 2621440);          //   655,360 B
  u16* Wp_bf = (u16*)(ws + 3276800);          //   655,360 B
  u16* Wo_bf = (u16*)(ws + 3932160);          // 1,310,720 B -> ends 5,242,880
  float* ep = (float*)(ws + 5242880);         // 5,242,880 B  [2048][640]
  float* pp = (float*)(ws + 10485760);        // 1,310,720 B  [512][640] -> ends 11,796,480
  u16* Wo_pk = (u16*)(ws + 11796480);         // 1,310,720 B packed fragments -> ends 13,107,200

  cast5_k<<<2048, 256, 0, stream>>>((const float4*)enc, (const float4*)pred,
                                    (const float4*)We, (const float4*)Wp,
                                    (const float4*)Wo, (ushort4*)ws);

  proj_k<<<dim3(16, 5), 256, 0, stream>>>(enc_bf, We_bf, ep);  // [2048][640]
  proj_k<<<dim3(4, 5), 256, 0, stream>>>(pred_bf, Wp_bf, pp);  // [512][640]
  pack_k<<<320, 256, 0, stream>>>(Wo_bf, Wo_pk);

  fused2_k<<<2048, 512, 0, stream>>>(ep, pp, Wo_pk, out);
}